// Round 1
// baseline (416.703 us; speedup 1.0000x reference)
//
#include <hip/hip_runtime.h>
#include <hip/hip_bf16.h>

// ---------------------------------------------------------------------------
// TransformerBlock: x[2,2048,1024] fp32 -> out fp32
//   QKV proj -> causal MHA (16 heads, dk=64) -> O proj -> LN1(residual)
//   -> FFN(4096, relu) -> LN2(residual)
// Strategy: bf16 MFMA GEMMs + flash attention, fp32 accumulate everywhere.
// ---------------------------------------------------------------------------

using f32x4 = __attribute__((ext_vector_type(4))) float;
using s16x8 = __attribute__((ext_vector_type(8))) short;

constexpr int D_MODEL = 1024;
constexpr int D_FF    = 4096;
constexpr int DK      = 64;
constexpr int BB      = 2;
constexpr int SS      = 2048;
constexpr int NTOK    = BB * SS;   // 4096

__device__ __forceinline__ ushort f2bf(float f) {
    unsigned u = __float_as_uint(f);
    u += 0x7fffu + ((u >> 16) & 1u);   // round-to-nearest-even
    return (ushort)(u >> 16);
}

// ---------------------------- fp32 -> bf16 convert -------------------------
__global__ void cvt_kernel(const float* __restrict__ in, ushort* __restrict__ out, int n) {
    int i = (blockIdx.x * blockDim.x + threadIdx.x) * 4;
    if (i + 3 < n) {
        float4 v = *(const float4*)(in + i);
        ushort4 o;
        o.x = f2bf(v.x); o.y = f2bf(v.y); o.z = f2bf(v.z); o.w = f2bf(v.w);
        *(ushort4*)(out + i) = o;
    }
}

// ---------------------------- GEMM: C = A * W^T + bias ---------------------
// A: [M,K] bf16 row-major. W: [N,K] bf16 row-major. C: [M,N] fp32 or bf16.
// 128x128 tile, BK=64, 4 waves (2x2), each wave 64x64 via 4x4 16x16x32 frags.
template <bool RELU, bool OUTBF16>
__global__ __launch_bounds__(256, 2) void gemm_bt(
        const ushort* __restrict__ A, const ushort* __restrict__ W,
        const float* __restrict__ bias, void* __restrict__ Cout,
        int M, int N, int K) {
    __shared__ __align__(16) char Asb[128 * 128];   // 128 rows x 64 bf16 (swizzled)
    __shared__ __align__(16) char Bsb[128 * 128];

    const int t  = threadIdx.x;
    const int l  = t & 63;
    const int w  = t >> 6;
    const int wr = w >> 1, wc = w & 1;
    const int li = l & 15, g = l >> 4;
    const int bm0 = blockIdx.y << 7;
    const int bn0 = blockIdx.x << 7;

    f32x4 acc[4][4];
#pragma unroll
    for (int m = 0; m < 4; ++m)
#pragma unroll
        for (int n = 0; n < 4; ++n)
            acc[m][n] = (f32x4){0.f, 0.f, 0.f, 0.f};

    const int srow = t >> 3;   // 0..31 within each i-group
    const int sslot = t & 7;

    for (int k0 = 0; k0 < K; k0 += 64) {
        __syncthreads();
#pragma unroll
        for (int i = 0; i < 4; ++i) {
            int row = i * 32 + srow;
            int off = row * 128 + ((sslot * 16) ^ ((row & 7) << 4));
            s16x8 av = *(const s16x8*)(A + (size_t)(bm0 + row) * K + k0 + sslot * 8);
            *(s16x8*)(Asb + off) = av;
            s16x8 bv = *(const s16x8*)(W + (size_t)(bn0 + row) * K + k0 + sslot * 8);
            *(s16x8*)(Bsb + off) = bv;
        }
        __syncthreads();
#pragma unroll
        for (int ks = 0; ks < 2; ++ks) {
            s16x8 af[4], bfr[4];
#pragma unroll
            for (int m = 0; m < 4; ++m) {
                int row = wr * 64 + m * 16 + li;
                af[m] = *(const s16x8*)(Asb + row * 128 + (((ks * 4 + g) * 16) ^ ((row & 7) << 4)));
            }
#pragma unroll
            for (int n = 0; n < 4; ++n) {
                int row = wc * 64 + n * 16 + li;
                bfr[n] = *(const s16x8*)(Bsb + row * 128 + (((ks * 4 + g) * 16) ^ ((row & 7) << 4)));
            }
#pragma unroll
            for (int m = 0; m < 4; ++m)
#pragma unroll
                for (int n = 0; n < 4; ++n)
                    acc[m][n] = __builtin_amdgcn_mfma_f32_16x16x32_bf16(af[m], bfr[n], acc[m][n], 0, 0, 0);
        }
    }

#pragma unroll
    for (int m = 0; m < 4; ++m) {
        int row0 = bm0 + wr * 64 + m * 16 + g * 4;
#pragma unroll
        for (int n = 0; n < 4; ++n) {
            int col = bn0 + wc * 64 + n * 16 + li;
            float bsv = bias[col];
#pragma unroll
            for (int r = 0; r < 4; ++r) {
                float v = acc[m][n][r] + bsv;
                if (RELU) v = fmaxf(v, 0.f);
                size_t idx = (size_t)(row0 + r) * N + col;
                if (OUTBF16) ((ushort*)Cout)[idx] = f2bf(v);
                else         ((float*)Cout)[idx]  = v;
            }
        }
    }
}

// ---------------------------- causal flash attention -----------------------
// One wave per 16 query rows of one (b,h). Q/K/V: [B,S,1024] bf16, head h at
// column h*64. Online softmax; P relayout via tiny swizzled LDS buffer.
__global__ __launch_bounds__(64) void attn_kernel(
        const ushort* __restrict__ Q, const ushort* __restrict__ Kx,
        const ushort* __restrict__ V, ushort* __restrict__ ctx) {
    const int l  = threadIdx.x;
    const int li = l & 15, g = l >> 4;
    const int q0 = blockIdx.x << 4;
    const int h  = blockIdx.y;
    const int b  = blockIdx.z;
    const size_t base = (size_t)b * SS * D_MODEL + h * DK;

    const ushort* Qp = Q + base + (size_t)q0 * D_MODEL;
    s16x8 qf[2];
#pragma unroll
    for (int ds = 0; ds < 2; ++ds)
        qf[ds] = *(const s16x8*)(Qp + li * D_MODEL + ds * 32 + g * 8);

    f32x4 o[4];
#pragma unroll
    for (int d = 0; d < 4; ++d) o[d] = (f32x4){0.f, 0.f, 0.f, 0.f};
    float m_[4], ls[4];
#pragma unroll
    for (int r = 0; r < 4; ++r) { m_[r] = -1e30f; ls[r] = 0.f; }

    __shared__ __align__(16) ushort Plds[16 * 32];

    for (int kt = 0; kt < q0 + 16; kt += 32) {
        const ushort* Kp = Kx + base + (size_t)kt * D_MODEL;
        const ushort* Vp = V  + base + (size_t)kt * D_MODEL;

        f32x4 sa[2];
        sa[0] = (f32x4){0.f, 0.f, 0.f, 0.f};
        sa[1] = (f32x4){0.f, 0.f, 0.f, 0.f};
#pragma unroll
        for (int ks = 0; ks < 2; ++ks)
#pragma unroll
            for (int ds = 0; ds < 2; ++ds) {
                s16x8 kf = *(const s16x8*)(Kp + (ks * 16 + li) * D_MODEL + ds * 32 + g * 8);
                sa[ks] = __builtin_amdgcn_mfma_f32_16x16x32_bf16(qf[ds], kf, sa[ks], 0, 0, 0);
            }

        float p[2][4];
#pragma unroll
        for (int ks = 0; ks < 2; ++ks)
#pragma unroll
            for (int r = 0; r < 4; ++r) {
                int col  = kt + ks * 16 + li;
                int rowq = q0 + g * 4 + r;
                float sv = sa[ks][r] * 0.125f;
                p[ks][r] = (col > rowq) ? -1e30f : sv;
            }

#pragma unroll
        for (int r = 0; r < 4; ++r) {
            float mx = fmaxf(p[0][r], p[1][r]);
            mx = fmaxf(mx, __shfl_xor(mx, 1));
            mx = fmaxf(mx, __shfl_xor(mx, 2));
            mx = fmaxf(mx, __shfl_xor(mx, 4));
            mx = fmaxf(mx, __shfl_xor(mx, 8));
            float nm = fmaxf(m_[r], mx);
            float fs = __expf(m_[r] - nm);
            m_[r] = nm;
            p[0][r] = __expf(p[0][r] - nm);
            p[1][r] = __expf(p[1][r] - nm);
            float rs_ = p[0][r] + p[1][r];
            rs_ += __shfl_xor(rs_, 1);
            rs_ += __shfl_xor(rs_, 2);
            rs_ += __shfl_xor(rs_, 4);
            rs_ += __shfl_xor(rs_, 8);
            ls[r] = ls[r] * fs + rs_;
            o[0][r] *= fs; o[1][r] *= fs; o[2][r] *= fs; o[3][r] *= fs;
        }

        // P (16x32) -> LDS bf16, XOR-swizzled in 16B slots
#pragma unroll
        for (int ks = 0; ks < 2; ++ks)
#pragma unroll
            for (int r = 0; r < 4; ++r) {
                int prow = g * 4 + r;
                int off  = prow * 64 + ((ks * 32 + li * 2) ^ ((prow & 3) << 4));
                *(ushort*)((char*)Plds + off) = f2bf(p[ks][r]);
            }
        __syncthreads();
        s16x8 pf = *(const s16x8*)((const char*)Plds + li * 64 + ((g * 16) ^ ((li & 3) << 4)));
#pragma unroll
        for (int d = 0; d < 4; ++d) {
            s16x8 vf;
#pragma unroll
            for (int j = 0; j < 8; ++j)
                vf[j] = (short)Vp[(size_t)(g * 8 + j) * D_MODEL + d * 16 + li];
            o[d] = __builtin_amdgcn_mfma_f32_16x16x32_bf16(pf, vf, o[d], 0, 0, 0);
        }
        __syncthreads();
    }

    ushort* cp = ctx + base + (size_t)q0 * D_MODEL;
#pragma unroll
    for (int r = 0; r < 4; ++r) {
        float inv = 1.0f / ls[r];
#pragma unroll
        for (int d = 0; d < 4; ++d)
            cp[(size_t)(g * 4 + r) * D_MODEL + d * 16 + li] = f2bf(o[d][r] * inv);
    }
}

// ---------------------------- residual + LayerNorm -------------------------
template <bool WBF>
__global__ __launch_bounds__(256) void ln_fused(
        const float* __restrict__ xa, const float* __restrict__ xb,
        const float* __restrict__ gamma, const float* __restrict__ beta,
        float* __restrict__ outf, ushort* __restrict__ outb) {
    const int row = blockIdx.x;
    const int t   = threadIdx.x;
    const size_t off = (size_t)row * D_MODEL + t * 4;
    float4 a = *(const float4*)(xa + off);
    float4 c = *(const float4*)(xb + off);
    float z0 = a.x + c.x, z1 = a.y + c.y, z2 = a.z + c.z, z3 = a.w + c.w;
    float sum = z0 + z1 + z2 + z3;
    float sq  = z0 * z0 + z1 * z1 + z2 * z2 + z3 * z3;
#pragma unroll
    for (int o = 1; o < 64; o <<= 1) {
        sum += __shfl_xor(sum, o);
        sq  += __shfl_xor(sq, o);
    }
    __shared__ float s1[4], s2[4];
    if ((t & 63) == 0) { s1[t >> 6] = sum; s2[t >> 6] = sq; }
    __syncthreads();
    float tot = s1[0] + s1[1] + s1[2] + s1[3];
    float tsq = s2[0] + s2[1] + s2[2] + s2[3];
    const float invn = 1.0f / (float)D_MODEL;
    float mu  = tot * invn;
    float var = tsq * invn - mu * mu;
    float rstd = rsqrtf(var + 1e-5f);
    float4 gv = *(const float4*)(gamma + t * 4);
    float4 bv = *(const float4*)(beta + t * 4);
    float y0 = (z0 - mu) * rstd * gv.x + bv.x;
    float y1 = (z1 - mu) * rstd * gv.y + bv.y;
    float y2 = (z2 - mu) * rstd * gv.z + bv.z;
    float y3 = (z3 - mu) * rstd * gv.w + bv.w;
    float4 y = {y0, y1, y2, y3};
    *(float4*)(outf + off) = y;
    if constexpr (WBF) {
        ushort4 u;
        u.x = f2bf(y0); u.y = f2bf(y1); u.z = f2bf(y2); u.w = f2bf(y3);
        *(ushort4*)(outb + off) = u;
    }
}

// ---------------------------------------------------------------------------
extern "C" void kernel_launch(void* const* d_in, const int* in_sizes, int n_in,
                              void* d_out, int out_size, void* d_ws, size_t ws_size,
                              hipStream_t stream) {
    const float* x   = (const float*)d_in[0];
    // d_in[1] = causal mask (implicit in kernel)
    const float* wq  = (const float*)d_in[2];  const float* bq  = (const float*)d_in[3];
    const float* wk  = (const float*)d_in[4];  const float* bk  = (const float*)d_in[5];
    const float* wv  = (const float*)d_in[6];  const float* bv  = (const float*)d_in[7];
    const float* wo  = (const float*)d_in[8];  const float* bo  = (const float*)d_in[9];
    const float* w1  = (const float*)d_in[10]; const float* b1  = (const float*)d_in[11];
    const float* w2  = (const float*)d_in[12]; const float* b2  = (const float*)d_in[13];
    const float* g1  = (const float*)d_in[14]; const float* be1 = (const float*)d_in[15];
    const float* g2  = (const float*)d_in[16]; const float* be2 = (const float*)d_in[17];
    float* out = (float*)d_out;

    char* ws = (char*)d_ws;
    const size_t MB = 1u << 20;
    ushort* wqb  = (ushort*)(ws + 0 * MB);    // 2MB
    ushort* wkb  = (ushort*)(ws + 2 * MB);
    ushort* wvb  = (ushort*)(ws + 4 * MB);
    ushort* wob  = (ushort*)(ws + 6 * MB);
    ushort* w1b  = (ushort*)(ws + 8 * MB);    // 8MB
    ushort* w2b  = (ushort*)(ws + 16 * MB);   // 8MB
    ushort* xb   = (ushort*)(ws + 24 * MB);   // 8MB
    ushort* Qb   = (ushort*)(ws + 32 * MB);   // 8MB
    ushort* Kb   = (ushort*)(ws + 40 * MB);
    ushort* Vb   = (ushort*)(ws + 48 * MB);
    ushort* ctx  = (ushort*)(ws + 56 * MB);   // 8MB
    float*  tmpf = (float*)(ws + 64 * MB);    // 16MB
    float*  h    = (float*)(ws + 80 * MB);    // 16MB
    ushort* hb   = (ushort*)(ws + 96 * MB);   // 8MB
    ushort* ffib = (ushort*)(ws + 104 * MB);  // 32MB -> 136MB total

    auto cvt = [&](const float* s, ushort* d, int n) {
        cvt_kernel<<<dim3(n / 1024), dim3(256), 0, stream>>>(s, d, n);
    };
    cvt(wq, wqb, D_MODEL * D_MODEL);
    cvt(wk, wkb, D_MODEL * D_MODEL);
    cvt(wv, wvb, D_MODEL * D_MODEL);
    cvt(wo, wob, D_MODEL * D_MODEL);
    cvt(w1, w1b, D_FF * D_MODEL);
    cvt(w2, w2b, D_MODEL * D_FF);
    cvt(x,  xb,  NTOK * D_MODEL);

    dim3 blk(256);
    gemm_bt<false, true><<<dim3(8, 32), blk, 0, stream>>>(xb, wqb, bq, Qb, NTOK, D_MODEL, D_MODEL);
    gemm_bt<false, true><<<dim3(8, 32), blk, 0, stream>>>(xb, wkb, bk, Kb, NTOK, D_MODEL, D_MODEL);
    gemm_bt<false, true><<<dim3(8, 32), blk, 0, stream>>>(xb, wvb, bv, Vb, NTOK, D_MODEL, D_MODEL);

    attn_kernel<<<dim3(SS / 16, 16, BB), dim3(64), 0, stream>>>(Qb, Kb, Vb, ctx);

    gemm_bt<false, false><<<dim3(8, 32), blk, 0, stream>>>(ctx, wob, bo, tmpf, NTOK, D_MODEL, D_MODEL);
    ln_fused<true><<<dim3(NTOK), blk, 0, stream>>>(x, tmpf, g1, be1, h, hb);
    gemm_bt<true, true><<<dim3(32, 32), blk, 0, stream>>>(hb, w1b, b1, ffib, NTOK, D_FF, D_MODEL);
    gemm_bt<false, false><<<dim3(8, 32), blk, 0, stream>>>(ffib, w2b, b2, tmpf, NTOK, D_MODEL, D_FF);
    ln_fused<false><<<dim3(NTOK), blk, 0, stream>>>(h, tmpf, g2, be2, out, nullptr);
}